// Round 1
// baseline (1232.483 us; speedup 1.0000x reference)
//
#include <hip/hip_runtime.h>
#include <math.h>

#define DI 384
#define NSEQ 256
#define BB 64
#define DOUT 512
#define SID 73920
#define EPSV 1e-5f

// ---------------- small kernels ----------------

__global__ __launch_bounds__(256) void k_weights(const float* __restrict__ graph,
                                                 float* __restrict__ W) {
  int row = blockIdx.x;  // b*NSEQ + n
  const float* g = graph + (size_t)row * NSEQ;
  float* w = W + (size_t)row * NSEQ;
  int t = threadIdx.x;
  float v = g[t];
  __shared__ float red[256];
  red[t] = v;
  __syncthreads();
  for (int s = 128; s > 0; s >>= 1) {
    if (t < s) red[t] += red[t + s];
    __syncthreads();
  }
  float deg = red[0] + EPSV;
  w[t] = v / deg;
}

__global__ __launch_bounds__(256) void k_colw(const float* __restrict__ W,
                                              float* __restrict__ colw) {
  int b = blockIdx.x;
  int j = threadIdx.x;
  const float* w = W + (size_t)b * NSEQ * NSEQ + j;
  float s = 0.f;
  for (int n = 0; n < NSEQ; n++) s += w[(size_t)n * NSEQ];
  colw[b * NSEQ + j] = s;
}

__global__ __launch_bounds__(384) void k_wmean(const float* __restrict__ colw,
                                               const float* __restrict__ tokens,
                                               float* __restrict__ wm) {
  int b = blockIdx.x;
  int d = threadIdx.x;  // 384
  const float* t = tokens + (size_t)b * NSEQ * DI + d;
  const float* cw = colw + b * NSEQ;
  float s = 0.f;
  for (int n = 0; n < NSEQ; n++) s += cw[n] * t[(size_t)n * DI];
  wm[b * DI + d] = s;
}

__global__ __launch_bounds__(256) void k_zc(const float* __restrict__ tokens,
                                            const float* __restrict__ wm,
                                            float* __restrict__ Z) {
  int idx = blockIdx.x * 256 + threadIdx.x;  // B*NSEQ*DI = 6291456
  int d = idx % DI;
  int b = idx / (NSEQ * DI);
  Z[idx] = tokens[idx] - wm[b * DI + d];
}

__global__ __launch_bounds__(256) void k_trace(const float* __restrict__ M2,
                                               float* __restrict__ tr) {
  int b = blockIdx.x;
  int t = threadIdx.x;
  float s = 0.f;
  for (int d = t; d < DI; d += 256)
    s += M2[(size_t)b * DI * DI + (size_t)d * DI + d];
  __shared__ float red[256];
  red[t] = s;
  __syncthreads();
  for (int st = 128; st > 0; st >>= 1) {
    if (t < st) red[t] += red[t + st];
    __syncthreads();
  }
  if (t == 0) tr[b] = red[0];
}

__global__ __launch_bounds__(256) void k_scale(float* __restrict__ Mbuf,
                                               const float* __restrict__ tr) {
  int idx = blockIdx.x * 256 + threadIdx.x;  // B*DI*DI
  int b = idx / (DI * DI);
  Mbuf[idx] = Mbuf[idx] / (tr[b] + EPSV);
}

// Y2 = 2.25 I - 1.875 Mn + 0.75 Mn^2 - 0.125 Mn^3   (in place over H)
__global__ __launch_bounds__(256) void k_y2(const float* __restrict__ Mn,
                                            const float* __restrict__ P1,
                                            float* __restrict__ H) {
  int idx = blockIdx.x * 256 + threadIdx.x;
  int r = (idx / DI) % DI, c = idx % DI;
  float v = -1.875f * Mn[idx] + 0.75f * P1[idx] - 0.125f * H[idx];
  if (r == c) v += 2.25f;
  H[idx] = v;
}

__global__ __launch_bounds__(256) void k_triu(const float* __restrict__ Y,
                                              const float* __restrict__ tr,
                                              float* __restrict__ V) {
  int i = blockIdx.x;  // row
  int b = blockIdx.y;
  float s = 1.0f / sqrtf(tr[b] + EPSV);
  // row i occupies [rowbase, rowbase + (DI - i)) with rowbase = i*DI - i*(i-1)/2
  long rowbase = (long)i * DI - (long)i * (i - 1) / 2;
  long vbase = (long)b * SID + rowbase - i;
  const float* y = Y + (size_t)b * DI * DI + (size_t)i * DI;
  for (int j = i + threadIdx.x; j < DI; j += 256) V[vbase + j] = y[j] * s;
}

// ---------------- GEMMs (fp32 vector, 64x64 tile, 4x4 microtile) ----------------

__global__ __launch_bounds__(256) void gemm_nn(const float* __restrict__ A,
                                               const float* __restrict__ Bm,
                                               float* __restrict__ C, int M, int N,
                                               int K, long sA, long sB, long sC,
                                               float alpha, float diagAdd) {
  int b = blockIdx.z;
  int n0 = blockIdx.x * 64, m0 = blockIdx.y * 64;
  const float* Ab = A + (size_t)b * sA;
  const float* Bb = Bm + (size_t)b * sB;
  float* Cb = C + (size_t)b * sC;
  __shared__ __align__(16) float lA[16][68];
  __shared__ __align__(16) float lB[16][68];
  int tid = threadIdx.x, tx = tid & 15, ty = tid >> 4;
  float acc[4][4] = {};
  for (int k0 = 0; k0 < K; k0 += 16) {
    for (int l = tid; l < 1024; l += 256) {
      int r = l >> 4, kk = l & 15;
      lA[kk][r] = Ab[(size_t)(m0 + r) * K + k0 + kk];
    }
    for (int l = tid; l < 1024; l += 256) {
      int kk = l >> 6, c = l & 63;
      lB[kk][c] = Bb[(size_t)(k0 + kk) * N + n0 + c];
    }
    __syncthreads();
#pragma unroll
    for (int kk = 0; kk < 16; kk++) {
      float4 a = *(const float4*)&lA[kk][ty * 4];
      float4 bb = *(const float4*)&lB[kk][tx * 4];
      acc[0][0] += a.x * bb.x; acc[0][1] += a.x * bb.y; acc[0][2] += a.x * bb.z; acc[0][3] += a.x * bb.w;
      acc[1][0] += a.y * bb.x; acc[1][1] += a.y * bb.y; acc[1][2] += a.y * bb.z; acc[1][3] += a.y * bb.w;
      acc[2][0] += a.z * bb.x; acc[2][1] += a.z * bb.y; acc[2][2] += a.z * bb.z; acc[2][3] += a.z * bb.w;
      acc[3][0] += a.w * bb.x; acc[3][1] += a.w * bb.y; acc[3][2] += a.w * bb.z; acc[3][3] += a.w * bb.w;
    }
    __syncthreads();
  }
#pragma unroll
  for (int i = 0; i < 4; i++)
#pragma unroll
    for (int j = 0; j < 4; j++) {
      int row = m0 + ty * 4 + i, col = n0 + tx * 4 + j;
      float v = alpha * acc[i][j];
      if (row == col) v += diagAdd;
      Cb[(size_t)row * N + col] = v;
    }
}

// C[m][n] = sum_k A[k][m] * B[k][n]  (A stored K x M)
__global__ __launch_bounds__(256) void gemm_tn(const float* __restrict__ A,
                                               const float* __restrict__ Bm,
                                               float* __restrict__ C, int M, int N,
                                               int K, long sA, long sB, long sC) {
  int b = blockIdx.z;
  int n0 = blockIdx.x * 64, m0 = blockIdx.y * 64;
  const float* Ab = A + (size_t)b * sA;
  const float* Bb = Bm + (size_t)b * sB;
  float* Cb = C + (size_t)b * sC;
  __shared__ __align__(16) float lA[16][68];
  __shared__ __align__(16) float lB[16][68];
  int tid = threadIdx.x, tx = tid & 15, ty = tid >> 4;
  float acc[4][4] = {};
  for (int k0 = 0; k0 < K; k0 += 16) {
    for (int l = tid; l < 1024; l += 256) {
      int kk = l >> 6, r = l & 63;
      lA[kk][r] = Ab[(size_t)(k0 + kk) * M + m0 + r];
    }
    for (int l = tid; l < 1024; l += 256) {
      int kk = l >> 6, c = l & 63;
      lB[kk][c] = Bb[(size_t)(k0 + kk) * N + n0 + c];
    }
    __syncthreads();
#pragma unroll
    for (int kk = 0; kk < 16; kk++) {
      float4 a = *(const float4*)&lA[kk][ty * 4];
      float4 bb = *(const float4*)&lB[kk][tx * 4];
      acc[0][0] += a.x * bb.x; acc[0][1] += a.x * bb.y; acc[0][2] += a.x * bb.z; acc[0][3] += a.x * bb.w;
      acc[1][0] += a.y * bb.x; acc[1][1] += a.y * bb.y; acc[1][2] += a.y * bb.z; acc[1][3] += a.y * bb.w;
      acc[2][0] += a.z * bb.x; acc[2][1] += a.z * bb.y; acc[2][2] += a.z * bb.z; acc[2][3] += a.z * bb.w;
      acc[3][0] += a.w * bb.x; acc[3][1] += a.w * bb.y; acc[3][2] += a.w * bb.z; acc[3][3] += a.w * bb.w;
    }
    __syncthreads();
  }
#pragma unroll
  for (int i = 0; i < 4; i++)
#pragma unroll
    for (int j = 0; j < 4; j++) {
      int row = m0 + ty * 4 + i, col = n0 + tx * 4 + j;
      Cb[(size_t)row * N + col] = acc[i][j];
    }
}

// ---------------- final FC: out = gelu(V @ W2 + b2) ----------------
#define KCHUNK 1120
#define NKC 66

__global__ __launch_bounds__(256) void k_fc(const float* __restrict__ V,
                                            const float* __restrict__ W2,
                                            float* __restrict__ part) {
  int ct = blockIdx.x;  // 0..7 (64 cols each)
  int kc = blockIdx.y;  // 0..65
  int c0 = ct * 64;
  int tid = threadIdx.x;
  int c = tid & 63, g = tid >> 6;  // g in 0..3
  __shared__ __align__(16) float vt[64][33];
  __shared__ __align__(16) float wt[32][64];
  float acc[16] = {};
  int ks0 = kc * KCHUNK;
  for (int ks = ks0; ks < ks0 + KCHUNK; ks += 32) {
    for (int l = tid; l < 2048; l += 256) {
      int m = l >> 5, kk = l & 31;
      vt[m][kk] = V[(size_t)m * SID + ks + kk];
    }
    for (int l = tid; l < 2048; l += 256) {
      int kk = l >> 6, cc = l & 63;
      wt[kk][cc] = W2[(size_t)(ks + kk) * DOUT + c0 + cc];
    }
    __syncthreads();
#pragma unroll 8
    for (int kk = 0; kk < 32; kk++) {
      float w = wt[kk][c];
#pragma unroll
      for (int i = 0; i < 16; i++) acc[i] += vt[g * 16 + i][kk] * w;
    }
    __syncthreads();
  }
  float* p = part + (size_t)kc * BB * DOUT;
#pragma unroll
  for (int i = 0; i < 16; i++) p[(size_t)(g * 16 + i) * DOUT + c0 + c] = acc[i];
}

__global__ __launch_bounds__(256) void k_reduce(const float* __restrict__ part,
                                                const float* __restrict__ b2,
                                                float* __restrict__ out) {
  int idx = blockIdx.x * 256 + threadIdx.x;  // 32768
  int c = idx & (DOUT - 1);
  float s = 0.f;
  for (int kc = 0; kc < NKC; kc++) s += part[(size_t)kc * BB * DOUT + idx];
  float x = s + b2[c];
  out[idx] = 0.5f * x * (1.0f + erff(x * 0.70710678118654752f));
}

// ---------------- launch ----------------

extern "C" void kernel_launch(void* const* d_in, const int* in_sizes, int n_in,
                              void* d_out, int out_size, void* d_ws, size_t ws_size,
                              hipStream_t stream) {
  (void)in_sizes; (void)n_in; (void)out_size; (void)ws_size;
  const float* tokens = (const float*)d_in[0];
  const float* graph = (const float*)d_in[1];
  const float* W2 = (const float*)d_in[2];
  const float* b2 = (const float*)d_in[3];

  float* ws = (float*)d_ws;
  const long NMAT = (long)BB * DI * DI;  // 9437184
  float* fM = ws;              // region 0: weights early, then M2/Mn, then Y3
  float* fA = ws + NMAT;       // region 1: Z early, then P1, then T, then V
  float* fB = ws + 2 * NMAT;   // region 2: WZ early, then H/Y2, then partials
  float* colw = ws + 3 * NMAT;           // 16384
  float* wm = colw + BB * NSEQ;          // 24576
  float* tr = wm + BB * DI;              // 64

  float* W = fM;
  float* Z = fA;
  float* WZ = fB;
  float* V = fA;
  float* part = fB;

  k_weights<<<BB * NSEQ, 256, 0, stream>>>(graph, W);
  k_colw<<<BB, 256, 0, stream>>>(W, colw);
  k_wmean<<<BB, 384, 0, stream>>>(colw, tokens, wm);
  k_zc<<<(BB * NSEQ * DI) / 256, 256, 0, stream>>>(tokens, wm, Z);

  // WZ = W @ Z  (M=256, N=384, K=256)
  gemm_nn<<<dim3(6, 4, BB), 256, 0, stream>>>(W, Z, WZ, 256, 384, 256,
                                              65536L, 98304L, 98304L, 1.f, 0.f);
  // M2 = Z^T @ WZ  (M=384, N=384, K=256)  -> fM
  gemm_tn<<<dim3(6, 6, BB), 256, 0, stream>>>(Z, WZ, fM, 384, 384, 256,
                                              98304L, 98304L, 147456L);
  k_trace<<<BB, 256, 0, stream>>>(fM, tr);
  k_scale<<<(int)(NMAT / 256), 256, 0, stream>>>(fM, tr);  // fM = Mn

  // P1 = Mn^2 -> fA
  gemm_nn<<<dim3(6, 6, BB), 256, 0, stream>>>(fM, fM, fA, 384, 384, 384,
                                              147456L, 147456L, 147456L, 1.f, 0.f);
  // H = Mn^3 -> fB
  gemm_nn<<<dim3(6, 6, BB), 256, 0, stream>>>(fM, fA, fB, 384, 384, 384,
                                              147456L, 147456L, 147456L, 1.f, 0.f);
  // Y2 = 2.25I - 1.875Mn + 0.75P1 - 0.125H  (in place in fB)
  k_y2<<<(int)(NMAT / 256), 256, 0, stream>>>(fM, fA, fB);
  // T = 3I - Mn @ Y2 -> fA
  gemm_nn<<<dim3(6, 6, BB), 256, 0, stream>>>(fM, fB, fA, 384, 384, 384,
                                              147456L, 147456L, 147456L, -1.f, 3.f);
  // Y3 = 0.5 * Y2 @ T -> fM
  gemm_nn<<<dim3(6, 6, BB), 256, 0, stream>>>(fB, fA, fM, 384, 384, 384,
                                              147456L, 147456L, 147456L, 0.5f, 0.f);

  // V = triu(Y3) / sqrt(tr + eps) -> fA
  k_triu<<<dim3(DI, BB), 256, 0, stream>>>(fM, tr, V);

  // out = gelu(V @ W2 + b2), split-K deterministic
  k_fc<<<dim3(8, NKC), 256, 0, stream>>>(V, W2, part);
  k_reduce<<<(BB * DOUT) / 256, 256, 0, stream>>>(part, b2, (float*)d_out);
}

// Round 2
// 649.642 us; speedup vs baseline: 1.8972x; 1.8972x over previous
//
#include <hip/hip_runtime.h>
#include <math.h>

#define DI 384
#define NSEQ 256
#define BB 64
#define DOUT 512
#define SID 73920
#define EPSV 1e-5f

typedef float f32x4 __attribute__((ext_vector_type(4)));
typedef short s16x8 __attribute__((ext_vector_type(8)));

// ---------------- small kernels ----------------

__global__ __launch_bounds__(256) void k_weights(const float* __restrict__ graph,
                                                 float* __restrict__ W) {
  int row = blockIdx.x;
  const float* g = graph + (size_t)row * NSEQ;
  float* w = W + (size_t)row * NSEQ;
  int t = threadIdx.x;
  float v = g[t];
  __shared__ float red[256];
  red[t] = v;
  __syncthreads();
  for (int s = 128; s > 0; s >>= 1) {
    if (t < s) red[t] += red[t + s];
    __syncthreads();
  }
  float deg = red[0] + EPSV;
  w[t] = v / deg;
}

__global__ __launch_bounds__(256) void k_colw(const float* __restrict__ W,
                                              float* __restrict__ colw) {
  int b = blockIdx.x;
  int j = threadIdx.x;
  const float* w = W + (size_t)b * NSEQ * NSEQ + j;
  float s = 0.f;
  for (int n = 0; n < NSEQ; n++) s += w[(size_t)n * NSEQ];
  colw[b * NSEQ + j] = s;
}

__global__ __launch_bounds__(384) void k_wmean(const float* __restrict__ colw,
                                               const float* __restrict__ tokens,
                                               float* __restrict__ wm) {
  int b = blockIdx.x;
  int d = threadIdx.x;
  const float* t = tokens + (size_t)b * NSEQ * DI + d;
  const float* cw = colw + b * NSEQ;
  float s = 0.f;
  for (int n = 0; n < NSEQ; n++) s += cw[n] * t[(size_t)n * DI];
  wm[b * DI + d] = s;
}

__global__ __launch_bounds__(256) void k_zc(const float* __restrict__ tokens,
                                            const float* __restrict__ wm,
                                            float* __restrict__ Z) {
  int idx = blockIdx.x * 256 + threadIdx.x;
  int d = idx % DI;
  int b = idx / (NSEQ * DI);
  Z[idx] = tokens[idx] - wm[b * DI + d];
}

__global__ __launch_bounds__(256) void k_trace(const float* __restrict__ M2,
                                               float* __restrict__ tr) {
  int b = blockIdx.x;
  int t = threadIdx.x;
  float s = 0.f;
  for (int d = t; d < DI; d += 256)
    s += M2[(size_t)b * DI * DI + (size_t)d * DI + d];
  __shared__ float red[256];
  red[t] = s;
  __syncthreads();
  for (int st = 128; st > 0; st >>= 1) {
    if (t < st) red[t] += red[t + st];
    __syncthreads();
  }
  if (t == 0) tr[b] = red[0];
}

__global__ __launch_bounds__(256) void k_scale2(const float* __restrict__ M2,
                                                const float* __restrict__ tr,
                                                float* __restrict__ Mn) {
  int idx = blockIdx.x * 256 + threadIdx.x;
  int b = idx / (DI * DI);
  Mn[idx] = M2[idx] / (tr[b] + EPSV);
}

// fp32 batched 384x384 transpose via LDS (coalesced both sides)
__global__ __launch_bounds__(256) void k_transpose(const float* __restrict__ X,
                                                   float* __restrict__ XT) {
  int b = blockIdx.z;
  int c0 = blockIdx.x * 64, r0 = blockIdx.y * 64;
  __shared__ float ld[64][68];
  const float* Xb = X + (size_t)b * 147456;
  float* Tb = XT + (size_t)b * 147456;
#pragma unroll
  for (int i = 0; i < 4; i++) {
    int sl = threadIdx.x + i * 256;
    int r = sl >> 4, q = sl & 15;
    *(float4*)&ld[r][q * 4] = *(const float4*)&Xb[(size_t)(r0 + r) * 384 + c0 + q * 4];
  }
  __syncthreads();
#pragma unroll
  for (int i = 0; i < 4; i++) {
    int sl = threadIdx.x + i * 256;
    int n = sl >> 4, q = sl & 15;
    float4 v;
    v.x = ld[q * 4 + 0][n];
    v.y = ld[q * 4 + 1][n];
    v.z = ld[q * 4 + 2][n];
    v.w = ld[q * 4 + 3][n];
    *(float4*)&Tb[(size_t)(c0 + n) * 384 + r0 + q * 4] = v;
  }
}

__global__ __launch_bounds__(256) void k_triu(const float* __restrict__ Y,
                                              const float* __restrict__ tr,
                                              float* __restrict__ V) {
  int i = blockIdx.x;
  int b = blockIdx.y;
  float s = 1.0f / sqrtf(tr[b] + EPSV);
  long rowbase = (long)i * DI - (long)i * (i - 1) / 2;
  long vbase = (long)b * SID + rowbase - i;
  const float* y = Y + (size_t)b * DI * DI + (size_t)i * DI;
  for (int j = i + threadIdx.x; j < DI; j += 256) V[vbase + j] = y[j] * s;
}

// ---------------- fp32 vector GEMMs (WZ, M2) ----------------

__global__ __launch_bounds__(256) void gemm_nn(const float* __restrict__ A,
                                               const float* __restrict__ Bm,
                                               float* __restrict__ C, int M, int N,
                                               int K, long sA, long sB, long sC,
                                               float alpha, float diagAdd) {
  int b = blockIdx.z;
  int n0 = blockIdx.x * 64, m0 = blockIdx.y * 64;
  const float* Ab = A + (size_t)b * sA;
  const float* Bb = Bm + (size_t)b * sB;
  float* Cb = C + (size_t)b * sC;
  __shared__ __align__(16) float lA[16][68];
  __shared__ __align__(16) float lB[16][68];
  int tid = threadIdx.x, tx = tid & 15, ty = tid >> 4;
  float acc[4][4] = {};
  for (int k0 = 0; k0 < K; k0 += 16) {
    for (int l = tid; l < 1024; l += 256) {
      int r = l >> 4, kk = l & 15;
      lA[kk][r] = Ab[(size_t)(m0 + r) * K + k0 + kk];
    }
    for (int l = tid; l < 1024; l += 256) {
      int kk = l >> 6, c = l & 63;
      lB[kk][c] = Bb[(size_t)(k0 + kk) * N + n0 + c];
    }
    __syncthreads();
#pragma unroll
    for (int kk = 0; kk < 16; kk++) {
      float4 a = *(const float4*)&lA[kk][ty * 4];
      float4 bb = *(const float4*)&lB[kk][tx * 4];
      acc[0][0] += a.x * bb.x; acc[0][1] += a.x * bb.y; acc[0][2] += a.x * bb.z; acc[0][3] += a.x * bb.w;
      acc[1][0] += a.y * bb.x; acc[1][1] += a.y * bb.y; acc[1][2] += a.y * bb.z; acc[1][3] += a.y * bb.w;
      acc[2][0] += a.z * bb.x; acc[2][1] += a.z * bb.y; acc[2][2] += a.z * bb.z; acc[2][3] += a.z * bb.w;
      acc[3][0] += a.w * bb.x; acc[3][1] += a.w * bb.y; acc[3][2] += a.w * bb.z; acc[3][3] += a.w * bb.w;
    }
    __syncthreads();
  }
#pragma unroll
  for (int i = 0; i < 4; i++)
#pragma unroll
    for (int j = 0; j < 4; j++) {
      int row = m0 + ty * 4 + i, col = n0 + tx * 4 + j;
      float v = alpha * acc[i][j];
      if (row == col) v += diagAdd;
      Cb[(size_t)row * N + col] = v;
    }
}

__global__ __launch_bounds__(256) void gemm_tn(const float* __restrict__ A,
                                               const float* __restrict__ Bm,
                                               float* __restrict__ C, int M, int N,
                                               int K, long sA, long sB, long sC) {
  int b = blockIdx.z;
  int n0 = blockIdx.x * 64, m0 = blockIdx.y * 64;
  const float* Ab = A + (size_t)b * sA;
  const float* Bb = Bm + (size_t)b * sB;
  float* Cb = C + (size_t)b * sC;
  __shared__ __align__(16) float lA[16][68];
  __shared__ __align__(16) float lB[16][68];
  int tid = threadIdx.x, tx = tid & 15, ty = tid >> 4;
  float acc[4][4] = {};
  for (int k0 = 0; k0 < K; k0 += 16) {
    for (int l = tid; l < 1024; l += 256) {
      int kk = l >> 6, r = l & 63;
      lA[kk][r] = Ab[(size_t)(k0 + kk) * M + m0 + r];
    }
    for (int l = tid; l < 1024; l += 256) {
      int kk = l >> 6, c = l & 63;
      lB[kk][c] = Bb[(size_t)(k0 + kk) * N + n0 + c];
    }
    __syncthreads();
#pragma unroll
    for (int kk = 0; kk < 16; kk++) {
      float4 a = *(const float4*)&lA[kk][ty * 4];
      float4 bb = *(const float4*)&lB[kk][tx * 4];
      acc[0][0] += a.x * bb.x; acc[0][1] += a.x * bb.y; acc[0][2] += a.x * bb.z; acc[0][3] += a.x * bb.w;
      acc[1][0] += a.y * bb.x; acc[1][1] += a.y * bb.y; acc[1][2] += a.y * bb.z; acc[1][3] += a.y * bb.w;
      acc[2][0] += a.z * bb.x; acc[2][1] += a.z * bb.y; acc[2][2] += a.z * bb.z; acc[2][3] += a.z * bb.w;
      acc[3][0] += a.w * bb.x; acc[3][1] += a.w * bb.y; acc[3][2] += a.w * bb.z; acc[3][3] += a.w * bb.w;
    }
    __syncthreads();
  }
#pragma unroll
  for (int i = 0; i < 4; i++)
#pragma unroll
    for (int j = 0; j < 4; j++) {
      int row = m0 + ty * 4 + i, col = n0 + tx * 4 + j;
      Cb[(size_t)row * N + col] = acc[i][j];
    }
}

// ---------------- split-bf16 MFMA NT-GEMM ----------------
// C[m][n] = sum_k A[m][k] * BT[n][k]   (384x384x384, batch 64)
// fp32 operands split on the fly into hi/mid/lo bf16; 6 MFMA passes.

__device__ __forceinline__ unsigned rnehi(float f, float& rem) {
  unsigned u = __float_as_uint(f);
  unsigned ho = u + 0x7FFFu + ((u >> 16) & 1u);
  float hf = __uint_as_float(ho & 0xFFFF0000u);
  rem = f - hf;
  return ho;
}

// reads 16 consecutive f32 at src; writes 16 bf16 to dst (hi), dst+4096 (mid), dst+8192 (lo)
__device__ __forceinline__ void stage16(const float* __restrict__ src, short* dst) {
  union U8 { unsigned u[4]; s16x8 v; };
  U8 H[2], M[2], L[2];
#pragma unroll
  for (int g = 0; g < 2; g++) {
    float v[8];
    *(float4*)&v[0] = *(const float4*)(src + g * 8);
    *(float4*)&v[4] = *(const float4*)(src + g * 8 + 4);
#pragma unroll
    for (int p = 0; p < 4; p++) {
      float r0, r1, q0, q1;
      unsigned h0 = rnehi(v[2 * p], r0), h1 = rnehi(v[2 * p + 1], r1);
      unsigned m0_ = rnehi(r0, q0), m1_ = rnehi(r1, q1);
      H[g].u[p] = __builtin_amdgcn_perm(h1, h0, 0x07060302u);
      M[g].u[p] = __builtin_amdgcn_perm(m1_, m0_, 0x07060302u);
      L[g].u[p] = __builtin_amdgcn_perm(__float_as_uint(q1), __float_as_uint(q0), 0x07060302u);
    }
  }
  *(s16x8*)(dst + 0) = H[0].v;
  *(s16x8*)(dst + 8) = H[1].v;
  *(s16x8*)(dst + 4096) = M[0].v;
  *(s16x8*)(dst + 4104) = M[1].v;
  *(s16x8*)(dst + 8192) = L[0].v;
  *(s16x8*)(dst + 8200) = L[1].v;
}

template <int MODE>  // 0: C = alpha*acc + diagAdd*I ; 1: fused Y2 epilogue (writes Y2T)
__global__ __launch_bounds__(256, 2) void gemm_nt(
    const float* __restrict__ pA, const float* __restrict__ pBT,
    float* __restrict__ pC, const float* __restrict__ pMn,
    const float* __restrict__ pP1T, float alpha, float diagAdd) {
  int b = blockIdx.z;
  int m0 = blockIdx.y * 128, n0 = blockIdx.x * 128;
  const float* Ab = pA + (size_t)b * 147456;
  const float* Bb = pBT + (size_t)b * 147456;
  __shared__ short As[3][128][32];
  __shared__ short Bs[3][128][32];
  int tid = threadIdx.x;
  int lane = tid & 63, wid = tid >> 6;
  int wm = wid >> 1, wn = wid & 1;
  int lr = lane & 15, lg = lane >> 4;
  int sr = tid >> 1, sh = (tid & 1) * 16;
  f32x4 acc[4][4] = {};

  for (int k0 = 0; k0 < 384; k0 += 32) {
    stage16(Ab + (size_t)(m0 + sr) * 384 + k0 + sh, &As[0][sr][sh]);
    stage16(Bb + (size_t)(n0 + sr) * 384 + k0 + sh, &Bs[0][sr][sh]);
    __syncthreads();

    s16x8 bf[3][4];
#pragma unroll
    for (int ib = 0; ib < 3; ib++)
#pragma unroll
      for (int ni = 0; ni < 4; ni++)
        bf[ib][ni] = *(const s16x8*)&Bs[ib][wn * 64 + ni * 16 + lr][lg * 8];

#pragma unroll
    for (int ia = 0; ia < 3; ia++) {
      s16x8 af[4];
#pragma unroll
      for (int mi = 0; mi < 4; mi++)
        af[mi] = *(const s16x8*)&As[ia][wm * 64 + mi * 16 + lr][lg * 8];
      const int nb = (ia == 0) ? 3 : (ia == 1) ? 2 : 1;
#pragma unroll
      for (int ib = 0; ib < nb; ib++)
#pragma unroll
        for (int ni = 0; ni < 4; ni++)
#pragma unroll
          for (int mi = 0; mi < 4; mi++)
            acc[mi][ni] = __builtin_amdgcn_mfma_f32_16x16x32_bf16(
                af[mi], bf[ib][ni], acc[mi][ni], 0, 0, 0);
    }
    __syncthreads();
  }

  const size_t cb = (size_t)b * 147456;
#pragma unroll
  for (int mi = 0; mi < 4; mi++)
#pragma unroll
    for (int ni = 0; ni < 4; ni++)
#pragma unroll
      for (int j = 0; j < 4; j++) {
        int row = m0 + wm * 64 + mi * 16 + lg * 4 + j;
        int col = n0 + wn * 64 + ni * 16 + lr;
        float v = acc[mi][ni][j];
        if (MODE == 0) {
          float o = alpha * v;
          if (row == col) o += diagAdd;
          pC[cb + (size_t)row * 384 + col] = o;
        } else {
          float mn = pMn[cb + (size_t)row * 384 + col];
          float p1 = pP1T[cb + (size_t)col * 384 + row];
          float y2 = -1.875f * mn + 0.75f * p1 - 0.125f * v;
          if (row == col) y2 += 2.25f;
          pC[cb + (size_t)col * 384 + row] = y2;  // Y2T
        }
      }
}

// ---------------- final FC: out = gelu(V @ W2 + b2) ----------------
#define FC_KSTEPS 5  // 5 x 64 = 320 k per chunk
#define FC_NCH 231   // 231 x 320 = 73920

__global__ __launch_bounds__(256) void k_fc(const float* __restrict__ V,
                                            const float* __restrict__ W2,
                                            float* __restrict__ part) {
  int ct = blockIdx.x;  // 8 col-tiles of 64
  int kc = blockIdx.y;  // 231 k-chunks
  __shared__ float vt[64][68];  // [k][m]
  __shared__ float wt[64][64];  // [k][c]
  int tid = threadIdx.x;
  int cq = tid & 15, rq = tid >> 4;
  float acc[4][4] = {};
  int ks0 = kc * 320;
  for (int s = 0; s < FC_KSTEPS; s++) {
    int ks = ks0 + s * 64;
#pragma unroll
    for (int i = 0; i < 4; i++) {
      int sl = tid + i * 256;
      int m = sl >> 4, k4 = sl & 15;
      float4 v = *(const float4*)&V[(size_t)m * SID + ks + k4 * 4];
      vt[k4 * 4 + 0][m] = v.x;
      vt[k4 * 4 + 1][m] = v.y;
      vt[k4 * 4 + 2][m] = v.z;
      vt[k4 * 4 + 3][m] = v.w;
      int kk = sl >> 4, q = sl & 15;
      *(float4*)&wt[kk][q * 4] = *(const float4*)&W2[(size_t)(ks + kk) * DOUT + ct * 64 + q * 4];
    }
    __syncthreads();
#pragma unroll 8
    for (int kk = 0; kk < 64; kk++) {
      float4 a = *(const float4*)&vt[kk][rq * 4];
      float4 w = *(const float4*)&wt[kk][cq * 4];
      acc[0][0] += a.x * w.x; acc[0][1] += a.x * w.y; acc[0][2] += a.x * w.z; acc[0][3] += a.x * w.w;
      acc[1][0] += a.y * w.x; acc[1][1] += a.y * w.y; acc[1][2] += a.y * w.z; acc[1][3] += a.y * w.w;
      acc[2][0] += a.z * w.x; acc[2][1] += a.z * w.y; acc[2][2] += a.z * w.z; acc[2][3] += a.z * w.w;
      acc[3][0] += a.w * w.x; acc[3][1] += a.w * w.y; acc[3][2] += a.w * w.z; acc[3][3] += a.w * w.w;
    }
    __syncthreads();
  }
  float* p = part + (size_t)kc * (BB * DOUT) + ct * 64;
#pragma unroll
  for (int i = 0; i < 4; i++)
#pragma unroll
    for (int j = 0; j < 4; j++)
      p[(size_t)(rq * 4 + i) * DOUT + cq * 4 + j] = acc[i][j];
}

__global__ __launch_bounds__(256) void k_reduce(const float* __restrict__ part,
                                                const float* __restrict__ b2,
                                                float* __restrict__ out) {
  int idx = blockIdx.x * 256 + threadIdx.x;  // 32768
  int c = idx & (DOUT - 1);
  float s = 0.f;
  for (int kc = 0; kc < FC_NCH; kc++) s += part[(size_t)kc * BB * DOUT + idx];
  float x = s + b2[c];
  out[idx] = 0.5f * x * (1.0f + erff(x * 0.70710678118654752f));
}

// ---------------- launch ----------------

extern "C" void kernel_launch(void* const* d_in, const int* in_sizes, int n_in,
                              void* d_out, int out_size, void* d_ws, size_t ws_size,
                              hipStream_t stream) {
  (void)in_sizes; (void)n_in; (void)out_size; (void)ws_size;
  const float* tokens = (const float*)d_in[0];
  const float* graph = (const float*)d_in[1];
  const float* W2 = (const float*)d_in[2];
  const float* b2 = (const float*)d_in[3];

  float* ws = (float*)d_ws;
  const long NM = 9437184L;  // 64*384*384
  float* sA = ws;             // Z -> MnN -> Y2N -> part
  float* sB = ws + NM;        // WZ -> MnT -> Y2T -> Y3
  float* sC = ws + 2 * NM;    // W -> M2 -> P1T -> TT -> V
  float* colw = ws + 3 * NM;
  float* wmv = colw + BB * NSEQ;
  float* trv = wmv + BB * DI;

  k_weights<<<BB * NSEQ, 256, 0, stream>>>(graph, sC);                 // W
  k_colw<<<BB, 256, 0, stream>>>(sC, colw);
  k_wmean<<<BB, 384, 0, stream>>>(colw, tokens, wmv);
  k_zc<<<(BB * NSEQ * DI) / 256, 256, 0, stream>>>(tokens, wmv, sA);   // Z

  // WZ = W @ Z
  gemm_nn<<<dim3(6, 4, BB), 256, 0, stream>>>(sC, sA, sB, 256, 384, 256,
                                              65536L, 98304L, 98304L, 1.f, 0.f);
  // M2 = Z^T @ WZ
  gemm_tn<<<dim3(6, 6, BB), 256, 0, stream>>>(sA, sB, sC, 384, 384, 256,
                                              98304L, 98304L, 147456L);
  k_trace<<<BB, 256, 0, stream>>>(sC, trv);
  k_scale2<<<(int)(NM / 256), 256, 0, stream>>>(sC, trv, sA);          // MnN
  k_transpose<<<dim3(6, 6, BB), 256, 0, stream>>>(sA, sB);             // MnT

  dim3 g33(3, 3, BB);
  // P1T = MnT * MnN^T  (= (Mn*Mn)^T)
  gemm_nt<0><<<g33, 256, 0, stream>>>(sB, sA, sC, nullptr, nullptr, 1.f, 0.f);
  // H = MnN * P1T^T ; fused epilogue writes Y2T = (2.25I -1.875Mn +0.75P1 -0.125H)^T
  gemm_nt<1><<<g33, 256, 0, stream>>>(sA, sC, sB, sA, sC, 0.f, 0.f);
  // TT = 3I - Y2T * MnN^T  (= (3I - Mn*Y2)^T)
  gemm_nt<0><<<g33, 256, 0, stream>>>(sB, sA, sC, nullptr, nullptr, -1.f, 3.f);
  // Y2N = transpose(Y2T)
  k_transpose<<<dim3(6, 6, BB), 256, 0, stream>>>(sB, sA);
  // Y3 = 0.5 * Y2N * TT^T  (= 0.5 * Y2 * T)
  gemm_nt<0><<<g33, 256, 0, stream>>>(sA, sC, sB, nullptr, nullptr, 0.5f, 0.f);

  // V = triu(Y3) / sqrt(tr + eps)
  k_triu<<<dim3(DI, BB), 256, 0, stream>>>(sB, trv, sC);

  // out = gelu(V @ W2 + b2)
  k_fc<<<dim3(8, FC_NCH), 256, 0, stream>>>(sC, W2, sA);
  k_reduce<<<(BB * DOUT) / 256, 256, 0, stream>>>(sA, b2, (float*)d_out);
}

// Round 3
// 537.959 us; speedup vs baseline: 2.2910x; 1.2076x over previous
//
#include <hip/hip_runtime.h>
#include <math.h>

#define DI 384
#define NSEQ 256
#define BB 64
#define DOUT 512
#define SID 73920
#define EPSV 1e-5f

typedef float f32x4 __attribute__((ext_vector_type(4)));
typedef short s16x8 __attribute__((ext_vector_type(8)));

// ---------------- small kernels ----------------

__global__ __launch_bounds__(256) void k_weights(const float* __restrict__ graph,
                                                 float* __restrict__ W) {
  int row = blockIdx.x;
  const float* g = graph + (size_t)row * NSEQ;
  float* w = W + (size_t)row * NSEQ;
  int t = threadIdx.x;
  float v = g[t];
  __shared__ float red[256];
  red[t] = v;
  __syncthreads();
  for (int s = 128; s > 0; s >>= 1) {
    if (t < s) red[t] += red[t + s];
    __syncthreads();
  }
  float deg = red[0] + EPSV;
  w[t] = v / deg;
}

__global__ __launch_bounds__(256) void k_colw(const float* __restrict__ W,
                                              float* __restrict__ colw) {
  int b = blockIdx.x;
  int j = threadIdx.x;
  const float* w = W + (size_t)b * NSEQ * NSEQ + j;
  float s = 0.f;
  for (int n = 0; n < NSEQ; n++) s += w[(size_t)n * NSEQ];
  colw[b * NSEQ + j] = s;
}

__global__ __launch_bounds__(384) void k_wmean(const float* __restrict__ colw,
                                               const float* __restrict__ tokens,
                                               float* __restrict__ wm) {
  int b = blockIdx.x;
  int d = threadIdx.x;
  const float* t = tokens + (size_t)b * NSEQ * DI + d;
  const float* cw = colw + b * NSEQ;
  float s = 0.f;
  for (int n = 0; n < NSEQ; n++) s += cw[n] * t[(size_t)n * DI];
  wm[b * DI + d] = s;
}

// ZT[b][d][n] = tokens[b][n][d] - wm[b][d]   (64x64 LDS tiles)
__global__ __launch_bounds__(256) void k_zcT(const float* __restrict__ tokens,
                                             const float* __restrict__ wm,
                                             float* __restrict__ ZT) {
  int b = blockIdx.z;
  int d0 = blockIdx.x * 64, n0 = blockIdx.y * 64;
  __shared__ float ld[64][68];
  const float* Tb = tokens + (size_t)b * NSEQ * DI;
  const float* wmb = wm + (size_t)b * DI;
  float* Zb = ZT + (size_t)b * DI * NSEQ;
#pragma unroll
  for (int i = 0; i < 4; i++) {
    int sl = threadIdx.x + i * 256;
    int r = sl >> 4, q = sl & 15;  // r = n-local, q*4 = d-local
    float4 v = *(const float4*)&Tb[(size_t)(n0 + r) * DI + d0 + q * 4];
    float4 m = *(const float4*)&wmb[d0 + q * 4];
    v.x -= m.x; v.y -= m.y; v.z -= m.z; v.w -= m.w;
    *(float4*)&ld[r][q * 4] = v;
  }
  __syncthreads();
#pragma unroll
  for (int i = 0; i < 4; i++) {
    int sl = threadIdx.x + i * 256;
    int dl = sl >> 4, q = sl & 15;  // dl = d-local, q*4 = n-local
    float4 v;
    v.x = ld[q * 4 + 0][dl];
    v.y = ld[q * 4 + 1][dl];
    v.z = ld[q * 4 + 2][dl];
    v.w = ld[q * 4 + 3][dl];
    *(float4*)&Zb[(size_t)(d0 + dl) * NSEQ + n0 + q * 4] = v;
  }
}

__global__ __launch_bounds__(256) void k_trace(const float* __restrict__ M2,
                                               float* __restrict__ tr) {
  int b = blockIdx.x;
  int t = threadIdx.x;
  float s = 0.f;
  for (int d = t; d < DI; d += 256)
    s += M2[(size_t)b * DI * DI + (size_t)d * DI + d];
  __shared__ float red[256];
  red[t] = s;
  __syncthreads();
  for (int st = 128; st > 0; st >>= 1) {
    if (t < st) red[t] += red[t + st];
    __syncthreads();
  }
  if (t == 0) tr[b] = red[0];
}

// MnN = M2/(tr+eps), MnT = transpose(MnN): one read, two writes.
__global__ __launch_bounds__(256) void k_scaleT(const float* __restrict__ M2,
                                                const float* __restrict__ tr,
                                                float* __restrict__ MnN,
                                                float* __restrict__ MnT) {
  int b = blockIdx.z;
  int c0 = blockIdx.x * 64, r0 = blockIdx.y * 64;
  __shared__ float ld[64][68];
  float inv = 1.0f / (tr[b] + EPSV);
  const float* Xb = M2 + (size_t)b * 147456;
  float* Nb = MnN + (size_t)b * 147456;
  float* Tb = MnT + (size_t)b * 147456;
#pragma unroll
  for (int i = 0; i < 4; i++) {
    int sl = threadIdx.x + i * 256;
    int r = sl >> 4, q = sl & 15;
    float4 v = *(const float4*)&Xb[(size_t)(r0 + r) * 384 + c0 + q * 4];
    v.x *= inv; v.y *= inv; v.z *= inv; v.w *= inv;
    *(float4*)&ld[r][q * 4] = v;
    *(float4*)&Nb[(size_t)(r0 + r) * 384 + c0 + q * 4] = v;
  }
  __syncthreads();
#pragma unroll
  for (int i = 0; i < 4; i++) {
    int sl = threadIdx.x + i * 256;
    int n = sl >> 4, q = sl & 15;
    float4 v;
    v.x = ld[q * 4 + 0][n];
    v.y = ld[q * 4 + 1][n];
    v.z = ld[q * 4 + 2][n];
    v.w = ld[q * 4 + 3][n];
    *(float4*)&Tb[(size_t)(c0 + n) * 384 + r0 + q * 4] = v;
  }
}

// fp32 batched 384x384 transpose via LDS
__global__ __launch_bounds__(256) void k_transpose(const float* __restrict__ X,
                                                   float* __restrict__ XT) {
  int b = blockIdx.z;
  int c0 = blockIdx.x * 64, r0 = blockIdx.y * 64;
  __shared__ float ld[64][68];
  const float* Xb = X + (size_t)b * 147456;
  float* Tb = XT + (size_t)b * 147456;
#pragma unroll
  for (int i = 0; i < 4; i++) {
    int sl = threadIdx.x + i * 256;
    int r = sl >> 4, q = sl & 15;
    *(float4*)&ld[r][q * 4] = *(const float4*)&Xb[(size_t)(r0 + r) * 384 + c0 + q * 4];
  }
  __syncthreads();
#pragma unroll
  for (int i = 0; i < 4; i++) {
    int sl = threadIdx.x + i * 256;
    int n = sl >> 4, q = sl & 15;
    float4 v;
    v.x = ld[q * 4 + 0][n];
    v.y = ld[q * 4 + 1][n];
    v.z = ld[q * 4 + 2][n];
    v.w = ld[q * 4 + 3][n];
    *(float4*)&Tb[(size_t)(c0 + n) * 384 + r0 + q * 4] = v;
  }
}

__global__ __launch_bounds__(256) void k_triu(const float* __restrict__ Y,
                                              const float* __restrict__ tr,
                                              float* __restrict__ V) {
  int i = blockIdx.x;
  int b = blockIdx.y;
  float s = 1.0f / sqrtf(tr[b] + EPSV);
  long rowbase = (long)i * DI - (long)i * (i - 1) / 2;
  long vbase = (long)b * SID + rowbase - i;
  const float* y = Y + (size_t)b * DI * DI + (size_t)i * DI;
  for (int j = i + threadIdx.x; j < DI; j += 256) V[vbase + j] = y[j] * s;
}

// ---------------- split-bf16 MFMA NT-GEMM ----------------
// C[m][n] = sum_k A[m][k] * BT[n][k]; fp32 operands split hi/mid/lo bf16, 6 passes.

__device__ __forceinline__ unsigned rnehi(float f, float& rem) {
  unsigned u = __float_as_uint(f);
  unsigned ho = u + 0x7FFFu + ((u >> 16) & 1u);
  float hf = __uint_as_float(ho & 0xFFFF0000u);
  rem = f - hf;
  return ho;
}

__device__ __forceinline__ void stage16(const float* __restrict__ src, short* dst) {
  union U8 { unsigned u[4]; s16x8 v; };
  U8 H[2], M[2], L[2];
#pragma unroll
  for (int g = 0; g < 2; g++) {
    float v[8];
    *(float4*)&v[0] = *(const float4*)(src + g * 8);
    *(float4*)&v[4] = *(const float4*)(src + g * 8 + 4);
#pragma unroll
    for (int p = 0; p < 4; p++) {
      float r0, r1, q0, q1;
      unsigned h0 = rnehi(v[2 * p], r0), h1 = rnehi(v[2 * p + 1], r1);
      unsigned m0_ = rnehi(r0, q0), m1_ = rnehi(r1, q1);
      H[g].u[p] = __builtin_amdgcn_perm(h1, h0, 0x07060302u);
      M[g].u[p] = __builtin_amdgcn_perm(m1_, m0_, 0x07060302u);
      L[g].u[p] = __builtin_amdgcn_perm(__float_as_uint(q1), __float_as_uint(q0), 0x07060302u);
    }
  }
  *(s16x8*)(dst + 0) = H[0].v;
  *(s16x8*)(dst + 8) = H[1].v;
  *(s16x8*)(dst + 4096) = M[0].v;
  *(s16x8*)(dst + 4104) = M[1].v;
  *(s16x8*)(dst + 8192) = L[0].v;
  *(s16x8*)(dst + 8200) = L[1].v;
}

template <int MODE>  // 0: C = alpha*acc + diagAdd*I ; 1: fused Y2 epilogue (writes Y2T)
__global__ __launch_bounds__(256, 2) void gemm_nt(
    const float* __restrict__ pA, const float* __restrict__ pBT,
    float* __restrict__ pC, const float* __restrict__ pMn,
    const float* __restrict__ pP1T, int K, int lda, int ldb, int ldc,
    long sA, long sB, long sC, float alpha, float diagAdd) {
  int b = blockIdx.z;
  int m0 = blockIdx.y * 128, n0 = blockIdx.x * 128;
  const float* Ab = pA + (size_t)b * sA;
  const float* Bb = pBT + (size_t)b * sB;
  __shared__ short As[3][128][32];
  __shared__ short Bs[3][128][32];
  int tid = threadIdx.x;
  int lane = tid & 63, wid = tid >> 6;
  int wm = wid >> 1, wn = wid & 1;
  int lr = lane & 15, lg = lane >> 4;
  int sr = tid >> 1, sh = (tid & 1) * 16;
  f32x4 acc[4][4] = {};

  for (int k0 = 0; k0 < K; k0 += 32) {
    stage16(Ab + (size_t)(m0 + sr) * lda + k0 + sh, &As[0][sr][sh]);
    stage16(Bb + (size_t)(n0 + sr) * ldb + k0 + sh, &Bs[0][sr][sh]);
    __syncthreads();

    s16x8 bf[3][4];
#pragma unroll
    for (int ib = 0; ib < 3; ib++)
#pragma unroll
      for (int ni = 0; ni < 4; ni++)
        bf[ib][ni] = *(const s16x8*)&Bs[ib][wn * 64 + ni * 16 + lr][lg * 8];

#pragma unroll
    for (int ia = 0; ia < 3; ia++) {
      s16x8 af[4];
#pragma unroll
      for (int mi = 0; mi < 4; mi++)
        af[mi] = *(const s16x8*)&As[ia][wm * 64 + mi * 16 + lr][lg * 8];
      const int nb = (ia == 0) ? 3 : (ia == 1) ? 2 : 1;
#pragma unroll
      for (int ib = 0; ib < nb; ib++)
#pragma unroll
        for (int ni = 0; ni < 4; ni++)
#pragma unroll
          for (int mi = 0; mi < 4; mi++)
            acc[mi][ni] = __builtin_amdgcn_mfma_f32_16x16x32_bf16(
                af[mi], bf[ib][ni], acc[mi][ni], 0, 0, 0);
    }
    __syncthreads();
  }

  const size_t cb = (size_t)b * sC;
#pragma unroll
  for (int mi = 0; mi < 4; mi++)
#pragma unroll
    for (int ni = 0; ni < 4; ni++)
#pragma unroll
      for (int j = 0; j < 4; j++) {
        int row = m0 + wm * 64 + mi * 16 + lg * 4 + j;
        int col = n0 + wn * 64 + ni * 16 + lr;
        float v = acc[mi][ni][j];
        if (MODE == 0) {
          float o = alpha * v;
          if (row == col) o += diagAdd;
          pC[cb + (size_t)row * ldc + col] = o;
        } else {
          float mn = pMn[cb + (size_t)row * 384 + col];
          float p1 = pP1T[cb + (size_t)col * 384 + row];
          float y2 = -1.875f * mn + 0.75f * p1 - 0.125f * v;
          if (row == col) y2 += 2.25f;
          pC[cb + (size_t)col * 384 + row] = y2;  // Y2T
        }
      }
}

// ---------------- final FC: out = gelu(V @ W2 + b2) ----------------
#define FC_KSTEPS 5  // 5 x 64 = 320 k per chunk
#define FC_NCH 231   // 231 x 320 = 73920

__global__ __launch_bounds__(256) void k_fc(const float* __restrict__ V,
                                            const float* __restrict__ W2,
                                            float* __restrict__ part) {
  int ct = blockIdx.x;  // 8 col-tiles of 64
  int kc = blockIdx.y;  // 231 k-chunks
  __shared__ float vt[64][68];  // [k][m]
  __shared__ float wt[64][64];  // [k][c]
  int tid = threadIdx.x;
  int cq = tid & 15, rq = tid >> 4;
  float acc[4][4] = {};
  int ks0 = kc * 320;
  for (int s = 0; s < FC_KSTEPS; s++) {
    int ks = ks0 + s * 64;
#pragma unroll
    for (int i = 0; i < 4; i++) {
      int sl = tid + i * 256;
      int m = sl >> 4, k4 = sl & 15;
      float4 v = *(const float4*)&V[(size_t)m * SID + ks + k4 * 4];
      vt[k4 * 4 + 0][m] = v.x;
      vt[k4 * 4 + 1][m] = v.y;
      vt[k4 * 4 + 2][m] = v.z;
      vt[k4 * 4 + 3][m] = v.w;
      int kk = sl >> 4, q = sl & 15;
      *(float4*)&wt[kk][q * 4] = *(const float4*)&W2[(size_t)(ks + kk) * DOUT + ct * 64 + q * 4];
    }
    __syncthreads();
#pragma unroll 8
    for (int kk = 0; kk < 64; kk++) {
      float4 a = *(const float4*)&vt[kk][rq * 4];
      float4 w = *(const float4*)&wt[kk][cq * 4];
      acc[0][0] += a.x * w.x; acc[0][1] += a.x * w.y; acc[0][2] += a.x * w.z; acc[0][3] += a.x * w.w;
      acc[1][0] += a.y * w.x; acc[1][1] += a.y * w.y; acc[1][2] += a.y * w.z; acc[1][3] += a.y * w.w;
      acc[2][0] += a.z * w.x; acc[2][1] += a.z * w.y; acc[2][2] += a.z * w.z; acc[2][3] += a.z * w.w;
      acc[3][0] += a.w * w.x; acc[3][1] += a.w * w.y; acc[3][2] += a.w * w.z; acc[3][3] += a.w * w.w;
    }
    __syncthreads();
  }
  float* p = part + (size_t)kc * (BB * DOUT) + ct * 64;
#pragma unroll
  for (int i = 0; i < 4; i++)
#pragma unroll
    for (int j = 0; j < 4; j++)
      p[(size_t)(rq * 4 + i) * DOUT + cq * 4 + j] = acc[i][j];
}

__global__ __launch_bounds__(256) void k_reduce(const float* __restrict__ part,
                                                const float* __restrict__ b2,
                                                float* __restrict__ out) {
  int idx = blockIdx.x * 256 + threadIdx.x;  // 32768
  int c = idx & (DOUT - 1);
  float s = 0.f;
  for (int kc = 0; kc < FC_NCH; kc++) s += part[(size_t)kc * BB * DOUT + idx];
  float x = s + b2[c];
  out[idx] = 0.5f * x * (1.0f + erff(x * 0.70710678118654752f));
}

// ---------------- launch ----------------

extern "C" void kernel_launch(void* const* d_in, const int* in_sizes, int n_in,
                              void* d_out, int out_size, void* d_ws, size_t ws_size,
                              hipStream_t stream) {
  (void)in_sizes; (void)n_in; (void)out_size; (void)ws_size;
  const float* tokens = (const float*)d_in[0];
  const float* graph = (const float*)d_in[1];
  const float* W2 = (const float*)d_in[2];
  const float* b2 = (const float*)d_in[3];

  float* ws = (float*)d_ws;
  const long NM = 9437184L;  // 64*384*384
  float* s0 = ws;             // W -> M2 -> P1T -> TT -> V -> (unused)
  float* s1 = ws + NM;        // ZT -> MnN -> Y2N -> part
  float* s2 = ws + 2 * NM;    // WZT -> MnT -> Y2T -> Y3
  float* colw = ws + 3 * NM;
  float* wmv = colw + BB * NSEQ;
  float* trv = wmv + BB * DI;

  k_weights<<<BB * NSEQ, 256, 0, stream>>>(graph, s0);                 // W
  k_colw<<<BB, 256, 0, stream>>>(s0, colw);
  k_wmean<<<BB, 384, 0, stream>>>(colw, tokens, wmv);
  k_zcT<<<dim3(6, 4, BB), 256, 0, stream>>>(tokens, wmv, s1);          // ZT (384x256)

  // WZT[e][n] = sum_k Z[k][e] W[n][k] : NT(A=ZT, B=W) -> s2 (384x256)
  gemm_nt<0><<<dim3(2, 3, BB), 256, 0, stream>>>(
      s1, s0, s2, nullptr, nullptr, 256, 256, 256, 256,
      98304L, 65536L, 98304L, 1.f, 0.f);
  // M2[d][e] = sum_n ZT[d][n] WZT[e][n] : NT(A=ZT, B=WZT) -> s0 (384x384)
  gemm_nt<0><<<dim3(3, 3, BB), 256, 0, stream>>>(
      s1, s2, s0, nullptr, nullptr, 256, 256, 256, 384,
      98304L, 98304L, 147456L, 1.f, 0.f);

  k_trace<<<BB, 256, 0, stream>>>(s0, trv);
  k_scaleT<<<dim3(6, 6, BB), 256, 0, stream>>>(s0, trv, s1, s2);       // MnN->s1, MnT->s2

  dim3 g33(3, 3, BB);
  // P1T = MnT * MnN^T -> s0
  gemm_nt<0><<<g33, 256, 0, stream>>>(s2, s1, s0, nullptr, nullptr, 384, 384, 384, 384,
                                      147456L, 147456L, 147456L, 1.f, 0.f);
  // H = MnN * P1T^T ; epilogue writes Y2T -> s2
  gemm_nt<1><<<g33, 256, 0, stream>>>(s1, s0, s2, s1, s0, 384, 384, 384, 384,
                                      147456L, 147456L, 147456L, 0.f, 0.f);
  // TT = 3I - Y2T * MnN^T -> s0
  gemm_nt<0><<<g33, 256, 0, stream>>>(s2, s1, s0, nullptr, nullptr, 384, 384, 384, 384,
                                      147456L, 147456L, 147456L, -1.f, 3.f);
  // Y2N = transpose(Y2T) -> s1
  k_transpose<<<dim3(6, 6, BB), 256, 0, stream>>>(s2, s1);
  // Y3 = 0.5 * Y2N * TT^T -> s2
  gemm_nt<0><<<g33, 256, 0, stream>>>(s1, s0, s2, nullptr, nullptr, 384, 384, 384, 384,
                                      147456L, 147456L, 147456L, 0.5f, 0.f);

  // V = triu(Y3) / sqrt(tr + eps) -> s0
  k_triu<<<dim3(DI, BB), 256, 0, stream>>>(s2, trv, s0);

  // out = gelu(V @ W2 + b2)
  k_fc<<<dim3(8, FC_NCH), 256, 0, stream>>>(s0, W2, s1);
  k_reduce<<<(BB * DOUT) / 256, 256, 0, stream>>>(s1, b2, (float*)d_out);
}